// Round 2
// baseline (1216.814 us; speedup 1.0000x reference)
//
#include <hip/hip_runtime.h>
#include <hip/hip_bf16.h>

// Vanilla tanh RNN. B=64, T=2048, I=64, H=128, fp32.
//   xw[b,t,h] = sum_i x[b,t,i]*W[h,i] + b_ih[h] + b_hh[h]
//   h_t = tanh(xw_t + h_{t-1} @ U^T);  outputs: ys [B,T,H], h_last [B,H]
//
// R2 changes (vs R1, scan was 1048us with 1228 cyc/step):
//  - chunk-staged xw/out in LDS (32 steps/chunk): no global ops inside the
//    step loop -> the compiler's vmcnt(0)-before-s_barrier drain no longer
//    puts L3 latency on the per-step critical path (was ~600 cyc/step).
//  - U pinned into VGPRs via asm tie (R1 VGPR_Count=48 proves it was
//    re-loaded from global every step).
//  - pair reduction via DPP quad_perm (R1's shfl_xor emitted ds_swizzle:
//    SQ_LDS_BANK_CONFLICT == 2^25 == exactly 1/thread/step).
//  - fast tanh: exp2+rcp, 4 instrs, saturates correctly at +-inf.

#define RNN_B 64
#define RNN_T 2048
#define RNN_I 64
#define RNN_H 128
#define CH    32            // timesteps per staged chunk
#define NCH   (RNN_T / CH)  // 64 chunks

__device__ __forceinline__ float fast_tanh(float x) {
  // tanh(x) = 1 - 2/(e^{2x}+1);  e^{2x} = exp2(x * 2*log2(e))
  float e = __builtin_amdgcn_exp2f(x * 2.885390081777927f);
  return 1.0f - 2.0f * __builtin_amdgcn_rcpf(e + 1.0f);
}

__device__ __forceinline__ float pair_sum(float s) {
  // add value from lane^1 via DPP quad_perm [1,0,3,2] — VALU pipe, no LDS
  int o = __builtin_amdgcn_mov_dpp(__float_as_int(s), 0xB1, 0xF, 0xF, true);
  return s + __int_as_float(o);
}

// ---------------------------------------------------------------------------
// Kernel 1: xw = x @ W^T + (b_ih + b_hh).  M=B*T=131072, N=128, K=64.
// ---------------------------------------------------------------------------
__global__ __launch_bounds__(256) void rnn_xw_gemm(
    const float* __restrict__ x, const float* __restrict__ W,
    const float* __restrict__ b_ih, const float* __restrict__ b_hh,
    float* __restrict__ xw) {
  const int tid = threadIdx.x;
  const int h  = tid & 127;   // output column
  const int rg = tid >> 7;    // row group (0/1)

  // W[h][0..63] into registers, pinned
  const float4* W4 = (const float4*)(W + h * RNN_I);
  float4 w4[16];
#pragma unroll
  for (int j = 0; j < 16; ++j) w4[j] = W4[j];
#pragma unroll
  for (int j = 0; j < 16; ++j)
    asm volatile("" : "+v"(w4[j].x), "+v"(w4[j].y), "+v"(w4[j].z), "+v"(w4[j].w));
  const float bias = b_ih[h] + b_hh[h];

  // Stage 64 rows of x (64x64 fp32 = 16 KB) into LDS, coalesced.
  __shared__ __align__(16) float4 xs[64 * 16];
  const long rbase = (long)blockIdx.x * 64;
  const float4* xg = (const float4*)(x + rbase * RNN_I);
#pragma unroll
  for (int j = 0; j < 4; ++j) xs[tid + 256 * j] = xg[tid + 256 * j];
  __syncthreads();

  // Each thread: 32 rows (stride 2), one column h. LDS reads broadcast.
  for (int rr = rg; rr < 64; rr += 2) {
    const float4* xr = xs + rr * 16;
    float4 a = make_float4(0.f, 0.f, 0.f, 0.f);
#pragma unroll
    for (int j = 0; j < 16; ++j) {
      float4 xv = xr[j];
      a.x = fmaf(w4[j].x, xv.x, a.x);
      a.y = fmaf(w4[j].y, xv.y, a.y);
      a.z = fmaf(w4[j].z, xv.z, a.z);
      a.w = fmaf(w4[j].w, xv.w, a.w);
    }
    float s = (a.x + a.y) + (a.z + a.w) + bias;
    xw[(rbase + rr) * RNN_H + h] = s;  // coalesced (consecutive h per lane)
  }
}

// ---------------------------------------------------------------------------
// Kernel 2: sequential scan, 1 block/batch, 256 threads (4 waves).
// thread -> (h = tid>>1, half = tid&1); 64 U coeffs in pinned registers;
// DPP pair-reduce; h double-buffered in LDS, 1 barrier/step;
// xw/out staged in LDS per 32-step chunk (no global ops inside steps).
// ---------------------------------------------------------------------------
__global__ __launch_bounds__(256, 1) void rnn_scan(
    const float* xw,            // aliases `out` — no __restrict__
    float* out, float* __restrict__ hlast,
    const float* __restrict__ h0, const float* __restrict__ U) {
  const int b    = blockIdx.x;
  const int tid  = threadIdx.x;
  const int h    = tid >> 1;
  const int half = tid & 1;

  __shared__ __align__(16) float hbuf[2][RNN_H];
  __shared__ __align__(16) float xbuf[CH * RNN_H];   // 16 KB
  __shared__ __align__(16) float obuf[CH * RNN_H];   // 16 KB

  // U[h][half*64 .. half*64+63] -> 16 float4 regs, pinned
  const float4* U4 = (const float4*)(U + h * RNN_H + half * 64);
  float4 u4[16];
#pragma unroll
  for (int j = 0; j < 16; ++j) u4[j] = U4[j];
#pragma unroll
  for (int j = 0; j < 16; ++j)
    asm volatile("" : "+v"(u4[j].x), "+v"(u4[j].y), "+v"(u4[j].z), "+v"(u4[j].w));

  if (tid < RNN_H) hbuf[0][tid] = h0[b * RNN_H + tid];

  const long base    = (long)b * RNN_T * RNN_H;
  const float4* xw4  = (const float4*)(xw + base);
  float4* out4       = (float4*)(out + base);
  float4* xb4        = (float4*)xbuf;
  const float4* ob4  = (const float4*)obuf;

  int cur = 0;
  float last = 0.f;
  for (int c = 0; c < NCH; ++c) {
    // Phase A: stage xw chunk c into LDS; flush out chunk c-1 from LDS.
    // (CH*H = 4096 floats = 1024 float4; 4 per thread)
    float4 xr[4];
#pragma unroll
    for (int j = 0; j < 4; ++j) xr[j] = xw4[(long)c * 1024 + tid + 256 * j];
    if (c > 0) {
      float4 orr[4];
#pragma unroll
      for (int j = 0; j < 4; ++j) orr[j] = ob4[tid + 256 * j];
#pragma unroll
      for (int j = 0; j < 4; ++j)
        out4[(long)(c - 1) * 1024 + tid + 256 * j] = orr[j];
    }
#pragma unroll
    for (int j = 0; j < 4; ++j) xb4[tid + 256 * j] = xr[j];
    __syncthreads();

    // Phase B: 32 steps, LDS-only traffic
    for (int tc = 0; tc < CH; ++tc) {
      const float4* hp = (const float4*)(&hbuf[cur][half * 64]);
      float4 a = make_float4(0.f, 0.f, 0.f, 0.f);
#pragma unroll
      for (int j = 0; j < 16; ++j) {
        float4 hv = hp[j];
        a.x = fmaf(u4[j].x, hv.x, a.x);
        a.y = fmaf(u4[j].y, hv.y, a.y);
        a.z = fmaf(u4[j].z, hv.z, a.z);
        a.w = fmaf(u4[j].w, hv.w, a.w);
      }
      float s = (a.x + a.y) + (a.z + a.w);
      s = pair_sum(s);                      // both pair lanes get full sum
      float val = fast_tanh(s + xbuf[tc * RNN_H + h]);
      if (half == 0) hbuf[cur ^ 1][h] = val;      // next-state
      else           obuf[tc * RNN_H + h] = val;  // output buffer
      last = val;
      cur ^= 1;
      __syncthreads();
    }
  }

  // Final chunk flush + h_last (last step's barrier makes obuf visible)
#pragma unroll
  for (int j = 0; j < 4; ++j)
    out4[(long)(NCH - 1) * 1024 + tid + 256 * j] = ob4[tid + 256 * j];
  if (half == 0) hlast[b * RNN_H + h] = last;
}

extern "C" void kernel_launch(void* const* d_in, const int* in_sizes, int n_in,
                              void* d_out, int out_size, void* d_ws, size_t ws_size,
                              hipStream_t stream) {
  const float* x    = (const float*)d_in[0];
  const float* h0   = (const float*)d_in[1];
  const float* W    = (const float*)d_in[2];
  const float* U    = (const float*)d_in[3];
  const float* b_ih = (const float*)d_in[4];
  const float* b_hh = (const float*)d_in[5];

  float* out   = (float*)d_out;                           // [B,T,H]
  float* hlast = out + (long)RNN_B * RNN_T * RNN_H;       // [B,H]

  // Stage 1: xw into the output region (read-before-write in scan, per chunk)
  rnn_xw_gemm<<<(RNN_B * RNN_T) / 64, 256, 0, stream>>>(x, W, b_ih, b_hh, out);
  // Stage 2: sequential recurrence, one block per batch element
  rnn_scan<<<RNN_B, 256, 0, stream>>>(out, out, hlast, h0, U);
}

// Round 3
// 1194.143 us; speedup vs baseline: 1.0190x; 1.0190x over previous
//
#include <hip/hip_runtime.h>
#include <hip/hip_bf16.h>

// Vanilla tanh RNN. B=64, T=2048, I=64, H=128, fp32.
//   xw[b,t,h] = sum_i x[b,t,i]*W[h,i] + b_ih[h] + b_hh[h]
//   h_t = tanh(xw_t + h_{t-1} @ U^T);  outputs: ys [B,T,H], h_last [B,H]
//
// R3: defeat U/W rematerialization. R2's VGPR_Count=52 proved the compiler
// re-loaded U from global inside the step loop (legal remat: __restrict__
// const). 4 waves x 16 x 1KB = 64KB/CU/step from L1/L2 ~= 1000 cyc/step =
// the whole observed cost. Fix: re-tie the register array with asm volatile
// INSIDE the outer loop — values become asm-defined, remat is illegal.

#define RNN_B 64
#define RNN_T 2048
#define RNN_I 64
#define RNN_H 128
#define CH    32            // timesteps per staged chunk
#define NCH   (RNN_T / CH)  // 64 chunks

#define TIE4(v) asm volatile("" : "+v"(v.x), "+v"(v.y), "+v"(v.z), "+v"(v.w))

__device__ __forceinline__ float fast_tanh(float x) {
  // tanh(x) = 1 - 2/(e^{2x}+1);  e^{2x} = exp2(x * 2*log2(e))
  float e = __builtin_amdgcn_exp2f(x * 2.885390081777927f);
  return 1.0f - 2.0f * __builtin_amdgcn_rcpf(e + 1.0f);
}

__device__ __forceinline__ float pair_sum(float s) {
  // add value from lane^1 via DPP quad_perm [1,0,3,2] — VALU pipe, no LDS
  int o = __builtin_amdgcn_mov_dpp(__float_as_int(s), 0xB1, 0xF, 0xF, true);
  return s + __int_as_float(o);
}

// ---------------------------------------------------------------------------
// Kernel 1: xw = x @ W^T + (b_ih + b_hh).  M=B*T=131072, N=128, K=64.
// ---------------------------------------------------------------------------
__global__ __launch_bounds__(256) void rnn_xw_gemm(
    const float* __restrict__ x, const float* __restrict__ W,
    const float* __restrict__ b_ih, const float* __restrict__ b_hh,
    float* __restrict__ xw) {
  const int tid = threadIdx.x;
  const int h  = tid & 127;   // output column
  const int rg = tid >> 7;    // row group (0/1)

  // W[h][0..63] into registers
  const float4* W4 = (const float4*)(W + h * RNN_I);
  float4 w4[16];
#pragma unroll
  for (int j = 0; j < 16; ++j) w4[j] = W4[j];
  const float bias = b_ih[h] + b_hh[h];

  // Stage 64 rows of x (64x64 fp32 = 16 KB) into LDS, coalesced.
  __shared__ __align__(16) float4 xs[64 * 16];
  const long rbase = (long)blockIdx.x * 64;
  const float4* xg = (const float4*)(x + rbase * RNN_I);
#pragma unroll
  for (int j = 0; j < 4; ++j) xs[tid + 256 * j] = xg[tid + 256 * j];
  __syncthreads();

  // Each thread: 32 rows (stride 2), one column h. LDS reads broadcast.
  for (int rr = rg; rr < 64; rr += 2) {
    // re-tie each row: forbids rematerializing the W loads in the loop
#pragma unroll
    for (int j = 0; j < 16; ++j) TIE4(w4[j]);
    const float4* xr = xs + rr * 16;
    float4 a = make_float4(0.f, 0.f, 0.f, 0.f);
#pragma unroll
    for (int j = 0; j < 16; ++j) {
      float4 xv = xr[j];
      a.x = fmaf(w4[j].x, xv.x, a.x);
      a.y = fmaf(w4[j].y, xv.y, a.y);
      a.z = fmaf(w4[j].z, xv.z, a.z);
      a.w = fmaf(w4[j].w, xv.w, a.w);
    }
    float s = (a.x + a.y) + (a.z + a.w) + bias;
    xw[(rbase + rr) * RNN_H + h] = s;  // coalesced (consecutive h per lane)
  }
}

// ---------------------------------------------------------------------------
// Kernel 2: sequential scan, 1 block/batch, 256 threads (4 waves).
// thread -> (h = tid>>1, half = tid&1); 64 U coeffs pinned in registers;
// DPP pair-reduce; h double-buffered in LDS, 1 barrier/step;
// xw/out staged in LDS per 32-step chunk (no global ops inside steps).
// ---------------------------------------------------------------------------
__global__ __launch_bounds__(256, 1) void rnn_scan(
    const float* xw,            // aliases `out` — no __restrict__
    float* out, float* __restrict__ hlast,
    const float* __restrict__ h0, const float* __restrict__ U) {
  const int b    = blockIdx.x;
  const int tid  = threadIdx.x;
  const int h    = tid >> 1;
  const int half = tid & 1;

  __shared__ __align__(16) float hbuf[2][RNN_H];
  __shared__ __align__(16) float xbuf[CH * RNN_H];   // 16 KB
  __shared__ __align__(16) float obuf[CH * RNN_H];   // 16 KB

  // U[h][half*64 .. half*64+63] -> 16 float4 regs
  const float4* U4 = (const float4*)(U + h * RNN_H + half * 64);
  float4 u4[16];
#pragma unroll
  for (int j = 0; j < 16; ++j) u4[j] = U4[j];

  if (tid < RNN_H) hbuf[0][tid] = h0[b * RNN_H + tid];

  const long base    = (long)b * RNN_T * RNN_H;
  const float4* xw4  = (const float4*)(xw + base);
  float4* out4       = (float4*)(out + base);
  float4* xb4        = (float4*)xbuf;
  const float4* ob4  = (const float4*)obuf;

  int cur = 0;
  float last = 0.f;
  for (int c = 0; c < NCH; ++c) {
    // re-tie U regs once per chunk: their def is now this asm, so the
    // allocator CANNOT rematerialize the global loads inside the step loop.
#pragma unroll
    for (int j = 0; j < 16; ++j) TIE4(u4[j]);

    // Phase A: stage xw chunk c into LDS; flush out chunk c-1 from LDS.
    // (CH*H = 4096 floats = 1024 float4; 4 per thread)
    float4 xr[4];
#pragma unroll
    for (int j = 0; j < 4; ++j) xr[j] = xw4[(long)c * 1024 + tid + 256 * j];
    if (c > 0) {
      float4 orr[4];
#pragma unroll
      for (int j = 0; j < 4; ++j) orr[j] = ob4[tid + 256 * j];
#pragma unroll
      for (int j = 0; j < 4; ++j)
        out4[(long)(c - 1) * 1024 + tid + 256 * j] = orr[j];
    }
#pragma unroll
    for (int j = 0; j < 4; ++j) xb4[tid + 256 * j] = xr[j];
    __syncthreads();

    // Phase B: 32 steps, LDS-only traffic
    for (int tc = 0; tc < CH; ++tc) {
      const float4* hp = (const float4*)(&hbuf[cur][half * 64]);
      float4 a = make_float4(0.f, 0.f, 0.f, 0.f);
#pragma unroll
      for (int j = 0; j < 16; ++j) {
        float4 hv = hp[j];
        a.x = fmaf(u4[j].x, hv.x, a.x);
        a.y = fmaf(u4[j].y, hv.y, a.y);
        a.z = fmaf(u4[j].z, hv.z, a.z);
        a.w = fmaf(u4[j].w, hv.w, a.w);
      }
      float s = (a.x + a.y) + (a.z + a.w);
      s = pair_sum(s);                      // both pair lanes get full sum
      float val = fast_tanh(s + xbuf[tc * RNN_H + h]);
      if (half == 0) hbuf[cur ^ 1][h] = val;      // next-state
      else           obuf[tc * RNN_H + h] = val;  // output buffer
      last = val;
      cur ^= 1;
      __syncthreads();
    }
  }

  // Final chunk flush + h_last (last step's barrier makes obuf visible)
#pragma unroll
  for (int j = 0; j < 4; ++j)
    out4[(long)(NCH - 1) * 1024 + tid + 256 * j] = ob4[tid + 256 * j];
  if (half == 0) hlast[b * RNN_H + h] = last;
}

extern "C" void kernel_launch(void* const* d_in, const int* in_sizes, int n_in,
                              void* d_out, int out_size, void* d_ws, size_t ws_size,
                              hipStream_t stream) {
  const float* x    = (const float*)d_in[0];
  const float* h0   = (const float*)d_in[1];
  const float* W    = (const float*)d_in[2];
  const float* U    = (const float*)d_in[3];
  const float* b_ih = (const float*)d_in[4];
  const float* b_hh = (const float*)d_in[5];

  float* out   = (float*)d_out;                           // [B,T,H]
  float* hlast = out + (long)RNN_B * RNN_T * RNN_H;       // [B,H]

  // Stage 1: xw into the output region (read-before-write in scan, per chunk)
  rnn_xw_gemm<<<(RNN_B * RNN_T) / 64, 256, 0, stream>>>(x, W, b_ih, b_hh, out);
  // Stage 2: sequential recurrence, one block per batch element
  rnn_scan<<<RNN_B, 256, 0, stream>>>(out, out, hlast, h0, U);
}

// Round 5
// 770.547 us; speedup vs baseline: 1.5792x; 1.5497x over previous
//
#include <hip/hip_runtime.h>
#include <hip/hip_bf16.h>

// Vanilla tanh RNN. B=64, T=2048, I=64, H=128, fp32.
//   xw[b,t,h] = sum_i x[b,t,i]*W[h,i] + b_ih[h] + b_hh[h]
//   h_t = tanh(xw_t + h_{t-1} @ U^T);  outputs: ys [B,T,H], h_last [B,H]
//
// R5 == R4 with the DPP ctrl made a template constant (compile fix).
// R4 theory: R1-R3 all ~1050us; VGPR_Count=52 (< the 64 needed for U alone)
// + ~2x ideal VALU issue => U never stayed in VGPRs; ~900 cyc/step stall =
// exposed reload/LDS latency at 1 wave/SIMD. Fix: shrink per-thread
// footprint so the allocator keeps U resident, and double waves/SIMD:
//   scan: 512 thr, thread -> (h=tid>>2, quarter q=tid&3), 8 float4 of U
//         (32 VGPRs), quad reduce via 2 DPP quad_perm adds, 2 waves/SIMD.
//   h-state LDS skewed: quarter q at float offset q*36 -> the 4 broadcast
//         groups hit disjoint bank quads (no 4-way conflict).
//   gemm: same pair-split (h=tid>>1, half k), 8 float4 of W per thread.

#define RNN_B 64
#define RNN_T 2048
#define RNN_I 64
#define RNN_H 128
#define CH    32            // timesteps per staged chunk
#define NCH   (RNN_T / CH)  // 64 chunks

__device__ __forceinline__ float fast_tanh(float x) {
  // tanh(x) = 1 - 2/(e^{2x}+1);  e^{2x} = exp2(x * 2*log2(e))
  float e = __builtin_amdgcn_exp2f(x * 2.885390081777927f);
  return 1.0f - 2.0f * __builtin_amdgcn_rcpf(e + 1.0f);
}

template <int CTRL>
__device__ __forceinline__ float dpp_add(float s) {
  int o = __builtin_amdgcn_mov_dpp(__float_as_int(s), CTRL, 0xF, 0xF, true);
  return s + __int_as_float(o);
}

// ---------------------------------------------------------------------------
// Kernel 1: xw = x @ W^T + (b_ih + b_hh).  M=B*T=131072, N=128, K=64.
// 2048 blocks x 256 threads, 64 rows/block.
// thread -> (h = tid>>1, half = tid&1): 32 W floats in regs (8 float4);
// pair-reduce with one DPP quad_perm; even lanes store (contiguous h).
// ---------------------------------------------------------------------------
__global__ __launch_bounds__(256) void rnn_xw_gemm(
    const float* __restrict__ x, const float* __restrict__ W,
    const float* __restrict__ b_ih, const float* __restrict__ b_hh,
    float* __restrict__ xw) {
  const int tid  = threadIdx.x;
  const int h    = tid >> 1;   // 0..127
  const int half = tid & 1;    // k-half

  // W[h][half*32 .. half*32+31] -> 8 float4 (32 VGPRs)
  const float4* W4 = (const float4*)(W + h * RNN_I + half * 32);
  float4 w[8];
#pragma unroll
  for (int j = 0; j < 8; ++j) w[j] = W4[j];
  const float bias = b_ih[h] + b_hh[h];

  // Stage 64 rows of x (64x64 fp32 = 16 KB) into LDS, coalesced.
  __shared__ __align__(16) float4 xs[64 * 16];
  const long rbase = (long)blockIdx.x * 64;
  const float4* xg = (const float4*)(x + rbase * RNN_I);
#pragma unroll
  for (int j = 0; j < 4; ++j) xs[tid + 256 * j] = xg[tid + 256 * j];
  __syncthreads();

  for (int r = 0; r < 64; ++r) {
    const float4* xr = xs + r * 16 + half * 8;
    float4 a = make_float4(0.f, 0.f, 0.f, 0.f);
#pragma unroll
    for (int j = 0; j < 8; ++j) {
      float4 xv = xr[j];
      a.x = fmaf(w[j].x, xv.x, a.x);
      a.y = fmaf(w[j].y, xv.y, a.y);
      a.z = fmaf(w[j].z, xv.z, a.z);
      a.w = fmaf(w[j].w, xv.w, a.w);
    }
    float s = (a.x + a.y) + (a.z + a.w);
    s = dpp_add<0xB1>(s);   // + lane^1: full 64-wide dot in both lanes
    if (half == 0)          // even lanes: h contiguous -> coalesced store
      xw[(rbase + r) * RNN_H + h] = s + bias;
  }
}

// ---------------------------------------------------------------------------
// Kernel 2: sequential scan. 1 block/batch, 512 threads (8 waves, 2/SIMD).
// thread -> (h = tid>>2, q = tid&3): 32 U floats in regs (8 float4);
// quad-reduce: DPP quad_perm xor1 (0xB1) + xor2 (0x4E).
// h state double-buffered in LDS with quarter-skew layout:
//   h[k] lives at float offset (k>>5)*36 + (k&31)   (bank-disjoint quads)
// xw/out chunk-staged in LDS (32 steps) -> no global ops inside steps.
// ---------------------------------------------------------------------------
__global__ __launch_bounds__(512, 2) void rnn_scan(
    const float* xw,            // aliases `out` — no __restrict__
    float* out, float* __restrict__ hlast,
    const float* __restrict__ h0, const float* __restrict__ U) {
  const int b   = blockIdx.x;
  const int tid = threadIdx.x;  // 0..511
  const int h   = tid >> 2;     // 0..127
  const int q   = tid & 3;      // k-quarter

  __shared__ __align__(16) float hbuf[2][4 * 36];    // 144 floats/buffer
  __shared__ __align__(16) float xbuf[CH * RNN_H];   // 16 KB
  __shared__ __align__(16) float obuf[CH * RNN_H];   // 16 KB

  // U[h][q*32 .. q*32+31] -> 8 float4 (32 VGPRs)
  const float4* U4 = (const float4*)(U + h * RNN_H + q * 32);
  float4 u[8];
#pragma unroll
  for (int j = 0; j < 8; ++j) u[j] = U4[j];

  if (tid < RNN_H) hbuf[0][(tid >> 5) * 36 + (tid & 31)] = h0[b * RNN_H + tid];

  const long base    = (long)b * RNN_T * RNN_H;
  const float4* xw4  = (const float4*)(xw + base);
  float4* out4       = (float4*)(out + base);
  float4* xb4        = (float4*)xbuf;
  const float4* ob4  = (const float4*)obuf;

  int cur = 0;
  for (int c = 0; c < NCH; ++c) {
    // Phase A: stage xw chunk c (1024 float4, 2/thread); flush out chunk c-1.
    float4 xr0 = xw4[(long)c * 1024 + tid];
    float4 xr1 = xw4[(long)c * 1024 + tid + 512];
    if (c > 0) {
      float4 o0 = ob4[tid];
      float4 o1 = ob4[tid + 512];
      out4[(long)(c - 1) * 1024 + tid]       = o0;
      out4[(long)(c - 1) * 1024 + tid + 512] = o1;
    }
    xb4[tid]       = xr0;
    xb4[tid + 512] = xr1;
    __syncthreads();

    // Phase B: 32 steps, LDS-only traffic
    for (int tc = 0; tc < CH; ++tc) {
      const float4* hp = (const float4*)(hbuf[cur] + q * 36);
      float4 a = make_float4(0.f, 0.f, 0.f, 0.f);
#pragma unroll
      for (int j = 0; j < 8; ++j) {
        float4 hv = hp[j];
        a.x = fmaf(u[j].x, hv.x, a.x);
        a.y = fmaf(u[j].y, hv.y, a.y);
        a.z = fmaf(u[j].z, hv.z, a.z);
        a.w = fmaf(u[j].w, hv.w, a.w);
      }
      float s = (a.x + a.y) + (a.z + a.w);
      s = dpp_add<0xB1>(s);  // + lane^1
      s = dpp_add<0x4E>(s);  // + lane^2: all 4 quad lanes hold full dot
      float val = fast_tanh(s + xbuf[tc * RNN_H + h]);
      if (q == 0) hbuf[cur ^ 1][(h >> 5) * 36 + (h & 31)] = val;  // next state
      if (q == 1) obuf[tc * RNN_H + h] = val;                     // output
      cur ^= 1;
      __syncthreads();
    }
  }

  // Final chunk flush + h_last (last step's barrier makes data visible)
  out4[(long)(NCH - 1) * 1024 + tid]       = ob4[tid];
  out4[(long)(NCH - 1) * 1024 + tid + 512] = ob4[tid + 512];
  if (tid < RNN_H)
    hlast[b * RNN_H + tid] = hbuf[cur][(tid >> 5) * 36 + (tid & 31)];
}

extern "C" void kernel_launch(void* const* d_in, const int* in_sizes, int n_in,
                              void* d_out, int out_size, void* d_ws, size_t ws_size,
                              hipStream_t stream) {
  const float* x    = (const float*)d_in[0];
  const float* h0   = (const float*)d_in[1];
  const float* W    = (const float*)d_in[2];
  const float* U    = (const float*)d_in[3];
  const float* b_ih = (const float*)d_in[4];
  const float* b_hh = (const float*)d_in[5];

  float* out   = (float*)d_out;                           // [B,T,H]
  float* hlast = out + (long)RNN_B * RNN_T * RNN_H;       // [B,H]

  // Stage 1: xw into the output region (read-before-write in scan, per chunk)
  rnn_xw_gemm<<<(RNN_B * RNN_T) / 64, 256, 0, stream>>>(x, W, b_ih, b_hh, out);
  // Stage 2: sequential recurrence, one block per batch element
  rnn_scan<<<RNN_B, 512, 0, stream>>>(out, out, hlast, h0, U);
}